// Round 4
// baseline (2980.338 us; speedup 1.0000x reference)
//
#include <hip/hip_runtime.h>
#include <hip/hip_bf16.h>

// TimeLSTM: B=2048, T=256, IN=65 (1 time-delta + 64 features), H=256, gates=1024.
//
// Round 4: register-resident W, 4-wave blocks.
// r2/r3 lesson: 8-wave (512-thr) blocks force 2 waves/SIMD => 256-reg/wave hard
// cap regardless of launch_bounds (r3: VGPR=128, FETCH 789MB = compiler
// rematerialized spilled W-frag loads from global EVERY step). Fix: 256-thr
// blocks (4 waves), 1 block/CU (LDS-forced) => 1 wave/SIMD => 512-reg budget.
//
// W (1024x320 bf16 = 640KB, pre-swizzled MFMA B-frag order), per-wave 160 frags:
//   kt 0..3 -> 64 frags in VGPRs (256 regs, loaded once)
//   kt 4..5 -> 32 frags/wave in LDS (4 waves x 32KB = 128KB, loaded once)
//   kt 6..9 -> 64 frags/wave streamed from L2 each step (256KB/CU/step),
//              4-frag groups, 3-deep lookahead (>=12 dwordx4 in flight).
// Step structure (r3's barrier placement, which is race-safe):
//   stage x_t -> barrierA -> read a[10]+tdv from LDS -> barrierB ->
//   [x(t+1) prefetch, stream prologue, MFMA kt0-9, epilogue, h->A] barrier-free.
//   (tdv MUST be read before barrierB: wave skew means another wave may reach
//    stage(t+1) and overwrite td_lds while this wave is still in epilogue(t).)
// C/D layout (m89): col = lane&15, row = (lane>>4)*4 + reg.
// Wave w owns cols w*64 + jt*16 + l15 (jt=0..3), gate g at acc[g*4+jt]:
// all 4 gates for a column live in one lane -> lane-local epilogue.

typedef __bf16 v8bf __attribute__((ext_vector_type(8)));
typedef __bf16 v4bf __attribute__((ext_vector_type(4)));
typedef float f32x4 __attribute__((ext_vector_type(4)));

#define B_SZ 2048
#define T_SZ 256
#define IN_SZ 65
#define NKT 10          // 320 / 32 k-steps
#define MBLK 16
#define NBLOCKS (B_SZ / MBLK)   // 128
#define THREADS 256
#define NW 4

#define WREG_KT 4                              // kt 0..3 in registers
#define LDSW_KT 2                              // kt 4..5 in LDS
#define SKT0 (WREG_KT + LDSW_KT)               // first streamed kt = 6
#define LDSW_BYTES (NW * LDSW_KT * 16 * 1024)  // 131072
#define A_STRIDE 328                           // 320 + 8 bf16 pad
#define A_BYTES (16 * A_STRIDE * 2)            // 10496
#define SMEM_TOTAL (LDSW_BYTES + A_BYTES + 64 + 64)   // 141696 <= 160K

__device__ __forceinline__ float fsig(float xv) {
    return __builtin_amdgcn_rcpf(1.f + __expf(-xv));
}
__device__ __forceinline__ float ftanh(float xv) {
    return fmaf(2.f, fsig(2.f * xv), -1.f);
}
// flat fragment id: wave w owns i = g*4 + jt (g=gate 0..3, jt=col-tile 0..3)
__device__ __forceinline__ int fid(int kt, int w, int i) {
    return (kt * 4 + w) * 16 + i;
}

// ---------------- prep: swizzle W into MFMA B-fragment order (bf16) ----------------
// 640 fragments (kt 0..9, w 0..3, i 0..15), 1KB each: total 640KB in d_ws.
// frag(kt,w,i): lane L holds W[n][k], n = (i>>2)*256 + w*64 + (i&3)*16 + (L&15),
//               k = kt*32 + (L>>4)*8 + j, j=0..7.
__global__ void prep_w(const float* __restrict__ W_ih, const float* __restrict__ W_hh,
                       __bf16* __restrict__ wsz) {
    int gtid = blockIdx.x * 256 + threadIdx.x;   // 0..40959
    int lane = gtid & 63;
    int frag = gtid >> 6;                        // 0..639
    int kt = frag >> 6;
    int w  = (frag >> 4) & 3;
    int nt = frag & 15;
    int g = nt >> 2, jt = nt & 3;
    int n  = g * 256 + w * 64 + jt * 16 + (lane & 15);
    int k0 = kt * 32 + ((lane >> 4) << 3);
    v8bf v;
#pragma unroll
    for (int j = 0; j < 8; ++j) {
        int k = k0 + j;
        float f = (k < 64) ? W_ih[n * 64 + k] : W_hh[n * 256 + (k - 64)];
        v[j] = (__bf16)f;
    }
    *reinterpret_cast<v8bf*>(wsz + (size_t)frag * 512 + lane * 8) = v;
}

// ---------------- fused persistent scan ----------------
__global__ __launch_bounds__(THREADS, 1) __attribute__((amdgpu_waves_per_eu(1)))
void tlstm_scan(
    const float* __restrict__ x, const __bf16* __restrict__ wsz,
    const float* __restrict__ b_ih, const float* __restrict__ b_hh,
    const float* __restrict__ Wt, const float* __restrict__ bt,
    const float* __restrict__ Wf, const float* __restrict__ bfp,
    float* __restrict__ out) {
    extern __shared__ char smem[];
    __bf16* ldsW  = reinterpret_cast<__bf16*>(smem);                       // 128KB
    __bf16* A     = reinterpret_cast<__bf16*>(smem + LDSW_BYTES);          // 16 x 328 bf16
    float* td_lds = reinterpret_cast<float*>(smem + LDSW_BYTES + A_BYTES); // 16 f32
    float* out_acc = reinterpret_cast<float*>(smem + LDSW_BYTES + A_BYTES + 64);

    const int tid  = threadIdx.x;
    const int lane = tid & 63;
    const int w    = tid >> 6;     // 0..3
    const int l15  = lane & 15;
    const int lhi  = lane >> 4;
    const int b0   = blockIdx.x * MBLK;

    const __bf16* wsz_l = wsz + (size_t)lane * 8;   // lane offset folded in

    // ---- one-time: register-resident W (kt 0..3): 64 frags = 256 VGPRs
    v8bf wreg[WREG_KT * 16];
#pragma unroll
    for (int kt = 0; kt < WREG_KT; ++kt)
#pragma unroll
        for (int i = 0; i < 16; ++i)
            wreg[kt * 16 + i] = *reinterpret_cast<const v8bf*>(
                wsz_l + (size_t)fid(kt, w, i) * 512);

    // ---- one-time: LDS-resident W (kt 4..5): this wave's 32 frags -> its LDS slab
#pragma unroll
    for (int kt = WREG_KT; kt < SKT0; ++kt)
#pragma unroll
        for (int i = 0; i < 16; ++i)
            *reinterpret_cast<uint4*>(
                ldsW + ((size_t)(w * 32 + (kt - WREG_KT) * 16 + i) * 64 + lane) * 8) =
                *reinterpret_cast<const uint4*>(wsz_l + (size_t)fid(kt, w, i) * 512);

    // zero A (h region must start at 0)
    for (int i = tid; i < 16 * A_STRIDE; i += THREADS) A[i] = (__bf16)0.f;
    if (tid < 16) out_acc[tid] = 0.f;

    // per-lane constants: 4 column slots jt=0..3 at col = w*64 + jt*16 + l15
    float bias[4][4], wt_r[4], bt_r[4], wf_r[4];
#pragma unroll
    for (int jt = 0; jt < 4; ++jt) {
        int col = w * 64 + jt * 16 + l15;
#pragma unroll
        for (int g = 0; g < 4; ++g) bias[g][jt] = b_ih[g * 256 + col] + b_hh[g * 256 + col];
        wt_r[jt] = Wt[col];
        bt_r[jt] = bt[col];
        wf_r[jt] = Wf[col];
    }

    float cst[4][4];   // fp32 cell state: [jt][reg]
#pragma unroll
    for (int jt = 0; jt < 4; ++jt)
#pragma unroll
        for (int r = 0; r < 4; ++r) cst[jt][r] = 0.f;
    float outp[4] = {0.f, 0.f, 0.f, 0.f};

    // x staging: 256 threads cover 16 rows x 16 chunks of 4 features
    const int xr = tid >> 4;   // row 0..15
    const int xc = tid & 15;   // feature quad 0..15
    const float* xbase = x + (size_t)(b0 + xr) * T_SZ * IN_SZ;

    // prefetch x(t=0)
    float px[4], ptd = 0.f;
    {
        const float* p = xbase;
#pragma unroll
        for (int j = 0; j < 4; ++j) px[j] = p[1 + xc * 4 + j];
        if (xc == 0) ptd = p[0];
    }

    __syncthreads();           // ldsW + A zero visible

    for (int t = 0; t < T_SZ; ++t) {
        // ---- stage x_t (from prefetch regs) + td into LDS
        {
            v4bf vv;
#pragma unroll
            for (int j = 0; j < 4; ++j) vv[j] = (__bf16)px[j];
            *reinterpret_cast<v4bf*>(A + xr * A_STRIDE + xc * 4) = vv;
            if (xc == 0) td_lds[xr] = ptd;
        }
        __syncthreads();   // barrier A: x_t + h(t-1) ready in LDS

        // ---- A fragments + tdv: ALL LDS reads of this step happen here
        v8bf a[NKT];
#pragma unroll
        for (int kt = 0; kt < NKT; ++kt)
            a[kt] = *reinterpret_cast<const v8bf*>(A + l15 * A_STRIDE + kt * 32 + lhi * 8);
        float tdv[4];
#pragma unroll
        for (int r = 0; r < 4; ++r) tdv[r] = td_lds[lhi * 4 + r];

        __syncthreads();   // barrier B: everything below is barrier-free
                           // until next barrier A (h/x writes only touch
                           // regions re-read after the NEXT barrier A).

        // ---- issue x(t+1) prefetch (overlaps GEMM)
        {
            int tn = (t + 1 < T_SZ) ? t + 1 : t;
            const float* p = xbase + (size_t)tn * IN_SZ;
#pragma unroll
            for (int j = 0; j < 4; ++j) px[j] = p[1 + xc * 4 + j];
            if (xc == 0) ptd = p[0];
        }

        f32x4 acc[16];
#pragma unroll
        for (int i = 0; i < 16; ++i) acc[i] = (f32x4){0.f, 0.f, 0.f, 0.f};

        // ---- stream prologue: groups 0..2 of kt 6 (12 dwordx4 in flight)
        v8bf bs[3][4];
#pragma unroll
        for (int s = 0; s < 3; ++s) {
            int kt = SKT0 + (s >> 2);
            int ib = (s & 3) * 4;
#pragma unroll
            for (int i = 0; i < 4; ++i)
                bs[s][i] = *reinterpret_cast<const v8bf*>(
                    wsz_l + (size_t)fid(kt, w, ib + i) * 512);
        }

        // ---- kt 0..3 from registers (hides stream latency)
#pragma unroll
        for (int kt = 0; kt < WREG_KT; ++kt)
#pragma unroll
            for (int i = 0; i < 16; ++i)
                acc[i] = __builtin_amdgcn_mfma_f32_16x16x32_bf16(
                    a[kt], wreg[kt * 16 + i], acc[i], 0, 0, 0);

        // ---- kt 4..5 from LDS
#pragma unroll
        for (int kt = WREG_KT; kt < SKT0; ++kt)
#pragma unroll
            for (int i = 0; i < 16; ++i) {
                v8bf b = *reinterpret_cast<const v8bf*>(
                    ldsW + ((size_t)(w * 32 + (kt - WREG_KT) * 16 + i) * 64 + lane) * 8);
                acc[i] = __builtin_amdgcn_mfma_f32_16x16x32_bf16(a[kt], b, acc[i], 0, 0, 0);
            }

        // ---- kt 6..9 streamed: 16 groups of 4 frags, 3-deep lookahead
#pragma unroll
        for (int s = 0; s < 16; ++s) {
            int kt = SKT0 + (s >> 2);
            int ib = (s & 3) * 4;
#pragma unroll
            for (int i = 0; i < 4; ++i)
                acc[ib + i] = __builtin_amdgcn_mfma_f32_16x16x32_bf16(
                    a[kt], bs[s % 3][i], acc[ib + i], 0, 0, 0);
            if (s < 13) {   // refill the buffer just consumed with group s+3
                int sn = s + 3;
                int kn = SKT0 + (sn >> 2);
                int ibn = (sn & 3) * 4;
#pragma unroll
                for (int i = 0; i < 4; ++i)
                    bs[s % 3][i] = *reinterpret_cast<const v8bf*>(
                        wsz_l + (size_t)fid(kn, w, ibn + i) * 512);
            }
        }

        // ---- lane-local LSTM epilogue (all 4 gates for this lane's 4 columns)
        const bool last = (t == T_SZ - 1);
#pragma unroll
        for (int jt = 0; jt < 4; ++jt) {
#pragma unroll
            for (int r = 0; r < 4; ++r) {
                float pi = acc[0 * 4 + jt][r] + bias[0][jt];
                float pf = acc[1 * 4 + jt][r] + bias[1][jt];
                float pg = acc[2 * 4 + jt][r] + bias[2][jt];
                float po = acc[3 * 4 + jt][r] + bias[3][jt];
                float d  = fsig(fmaf(tdv[r], wt_r[jt], bt_r[jt]));
                float c  = cst[jt][r] * d;                    // c *= decay
                c = fsig(pf) * c + fsig(pi) * ftanh(pg);      // c = f*c + i*g
                cst[jt][r] = c;
                float h = fsig(po) * ftanh(c);                // h = o*tanh(c)
                int row = lhi * 4 + r;
                int col = w * 64 + jt * 16 + l15;
                A[row * A_STRIDE + 64 + col] = (__bf16)h;     // h -> A layout for next step
                if (last) outp[r] = fmaf(h, wf_r[jt], outp[r]);
            }
        }
    }

    // ---- output: out[b] = h_T . Wf + bf
#pragma unroll
    for (int r = 0; r < 4; ++r) atomicAdd(&out_acc[lhi * 4 + r], outp[r]);
    __syncthreads();
    if (tid < 16) out[b0 + tid] = out_acc[tid] + bfp[0];
}

extern "C" void kernel_launch(void* const* d_in, const int* in_sizes, int n_in,
                              void* d_out, int out_size, void* d_ws, size_t ws_size,
                              hipStream_t stream) {
    const float* x    = (const float*)d_in[0];
    const float* W_ih = (const float*)d_in[1];
    const float* W_hh = (const float*)d_in[2];
    const float* b_ih = (const float*)d_in[3];
    const float* b_hh = (const float*)d_in[4];
    const float* Wt   = (const float*)d_in[5];
    const float* bt   = (const float*)d_in[6];
    const float* Wf   = (const float*)d_in[7];
    const float* bfp  = (const float*)d_in[8];
    float* out  = (float*)d_out;
    __bf16* wsz = (__bf16*)d_ws;   // 640KB of swizzled bf16 W

    (void)in_sizes; (void)n_in; (void)out_size; (void)ws_size;

    hipFuncSetAttribute(reinterpret_cast<const void*>(tlstm_scan),
                        hipFuncAttributeMaxDynamicSharedMemorySize, SMEM_TOTAL);

    prep_w<<<dim3(160), dim3(256), 0, stream>>>(W_ih, W_hh, wsz);
    tlstm_scan<<<dim3(NBLOCKS), dim3(THREADS), SMEM_TOTAL, stream>>>(
        x, wsz, b_ih, b_hh, Wt, bt, Wf, bfp, out);
}

// Round 5
// 2197.284 us; speedup vs baseline: 1.3564x; 1.3564x over previous
//
#include <hip/hip_runtime.h>
#include <hip/hip_bf16.h>

// TimeLSTM: B=2048, T=256, IN=65 (1 time-delta + 64 features), H=256, gates=1024.
//
// Round 5: make the register W-tier REAL.
// r4 failure: global_load can't write AGPRs and LLVM only auto-AGPRs MFMA
// accumulators, so wreg[256 regs] fought acc/a/epilogue for the 256-reg arch
// file -> scratch spills (L2-absorbed, invisible in FETCH). Fix: inline-asm
// MFMA with "a" constraint on the B operand -> wreg lives in AGPRs (exactly
// 256), arch VGPRs ~230 for everything else. Also:
//  - A_STRIDE 328->344 bf16 (688B rows, 16B-aligned => real ds_read_b128;
//    328*2=656B was misaligned since r1 -> scalar ds_read_u16 chains).
//  - stream prologue issued before x-prefetch; 2-deep 4-frag lookahead.
// Tiers per wave (160 frags x 1KB): kt 0..3 AGPR (64 frags), kt 4..5 LDS
// (128KB block-wide), kt 6..9 streamed from L2 (256KB/CU/step).
// Step: stage x_t -> barrierA -> read a[10]+tdv -> barrierB ->
//       [stream prologue, x(t+1) prefetch, MFMA reg/LDS/stream, epilogue, h->A].
// C/D layout (m89): col = lane&15, row = (lane>>4)*4 + reg. Wave w owns cols
// w*64 + jt*16 + l15; all 4 gates of a column in one lane -> lane-local epilogue.

typedef __bf16 v8bf __attribute__((ext_vector_type(8)));
typedef __bf16 v4bf __attribute__((ext_vector_type(4)));
typedef float f32x4 __attribute__((ext_vector_type(4)));
typedef int   v4i  __attribute__((ext_vector_type(4)));

#define B_SZ 2048
#define T_SZ 256
#define IN_SZ 65
#define NKT 10          // 320 / 32 k-steps
#define MBLK 16
#define NBLOCKS (B_SZ / MBLK)   // 128
#define THREADS 256
#define NW 4

#define WREG_KT 4                              // kt 0..3 in AGPRs
#define LDSW_KT 2                              // kt 4..5 in LDS
#define SKT0 (WREG_KT + LDSW_KT)               // first streamed kt = 6
#define LDSW_BYTES (NW * LDSW_KT * 16 * 1024)  // 131072
#define A_STRIDE 344                           // bf16 elems; 688B rows: 16B-aligned, <=2-way banks
#define A_BYTES (16 * A_STRIDE * 2)            // 11008
#define SMEM_TOTAL (LDSW_BYTES + A_BYTES + 64 + 64)   // 142208 <= 160K

__device__ __forceinline__ float fsig(float xv) {
    return __builtin_amdgcn_rcpf(1.f + __expf(-xv));
}
__device__ __forceinline__ float ftanh(float xv) {
    return fmaf(2.f, fsig(2.f * xv), -1.f);
}
// B operand pinned to AGPR ("a") -> W tier genuinely register-resident.
__device__ __forceinline__ void mfma_a(f32x4& acc, v4i av, v4i bv) {
    asm("v_mfma_f32_16x16x32_bf16 %0, %1, %2, %0" : "+v"(acc) : "v"(av), "a"(bv));
}
__device__ __forceinline__ void mfma_v(f32x4& acc, v4i av, v4i bv) {
    asm("v_mfma_f32_16x16x32_bf16 %0, %1, %2, %0" : "+v"(acc) : "v"(av), "v"(bv));
}
// flat fragment id: wave w owns i = g*4 + jt (g=gate 0..3, jt=col-tile 0..3)
__device__ __forceinline__ int fid(int kt, int w, int i) {
    return (kt * 4 + w) * 16 + i;
}

// ---------------- prep: swizzle W into MFMA B-fragment order (bf16) ----------------
// 640 fragments (kt 0..9, w 0..3, i 0..15), 1KB each: total 640KB in d_ws.
// frag(kt,w,i): lane L holds W[n][k], n = (i>>2)*256 + w*64 + (i&3)*16 + (L&15),
//               k = kt*32 + (L>>4)*8 + j, j=0..7.
__global__ void prep_w(const float* __restrict__ W_ih, const float* __restrict__ W_hh,
                       __bf16* __restrict__ wsz) {
    int gtid = blockIdx.x * 256 + threadIdx.x;   // 0..40959
    int lane = gtid & 63;
    int frag = gtid >> 6;                        // 0..639
    int kt = frag >> 6;
    int w  = (frag >> 4) & 3;
    int nt = frag & 15;
    int g = nt >> 2, jt = nt & 3;
    int n  = g * 256 + w * 64 + jt * 16 + (lane & 15);
    int k0 = kt * 32 + ((lane >> 4) << 3);
    v8bf v;
#pragma unroll
    for (int j = 0; j < 8; ++j) {
        int k = k0 + j;
        float f = (k < 64) ? W_ih[n * 64 + k] : W_hh[n * 256 + (k - 64)];
        v[j] = (__bf16)f;
    }
    *reinterpret_cast<v8bf*>(wsz + (size_t)frag * 512 + lane * 8) = v;
}

// ---------------- fused persistent scan ----------------
__global__ __launch_bounds__(THREADS, 1) __attribute__((amdgpu_waves_per_eu(1)))
void tlstm_scan(
    const float* __restrict__ x, const __bf16* __restrict__ wsz,
    const float* __restrict__ b_ih, const float* __restrict__ b_hh,
    const float* __restrict__ Wt, const float* __restrict__ bt,
    const float* __restrict__ Wf, const float* __restrict__ bfp,
    float* __restrict__ out) {
    extern __shared__ char smem[];
    __bf16* ldsW  = reinterpret_cast<__bf16*>(smem);                       // 128KB
    __bf16* A     = reinterpret_cast<__bf16*>(smem + LDSW_BYTES);          // 16 x 344 bf16
    float* td_lds = reinterpret_cast<float*>(smem + LDSW_BYTES + A_BYTES); // 16 f32
    float* out_acc = reinterpret_cast<float*>(smem + LDSW_BYTES + A_BYTES + 64);

    const int tid  = threadIdx.x;
    const int lane = tid & 63;
    const int w    = tid >> 6;     // 0..3
    const int l15  = lane & 15;
    const int lhi  = lane >> 4;
    const int b0   = blockIdx.x * MBLK;

    const __bf16* wsz_l = wsz + (size_t)lane * 8;   // lane offset folded in

    // ---- one-time: W kt 0..3 -> wreg (pinned to AGPRs by mfma_a's "a" use)
    v4i wreg[WREG_KT * 16];
#pragma unroll
    for (int kt = 0; kt < WREG_KT; ++kt)
#pragma unroll
        for (int i = 0; i < 16; ++i)
            wreg[kt * 16 + i] = *reinterpret_cast<const v4i*>(
                wsz_l + (size_t)fid(kt, w, i) * 512);

    // ---- one-time: W kt 4..5 -> this wave's LDS slab
#pragma unroll
    for (int kt = WREG_KT; kt < SKT0; ++kt)
#pragma unroll
        for (int i = 0; i < 16; ++i)
            *reinterpret_cast<v4i*>(
                ldsW + ((size_t)(w * 32 + (kt - WREG_KT) * 16 + i) * 64 + lane) * 8) =
                *reinterpret_cast<const v4i*>(wsz_l + (size_t)fid(kt, w, i) * 512);

    // zero A (h region must start at 0)
    for (int i = tid; i < 16 * A_STRIDE; i += THREADS) A[i] = (__bf16)0.f;
    if (tid < 16) out_acc[tid] = 0.f;

    // per-lane constants: 4 column slots jt=0..3 at col = w*64 + jt*16 + l15
    float bias[4][4], wt_r[4], bt_r[4], wf_r[4];
#pragma unroll
    for (int jt = 0; jt < 4; ++jt) {
        int col = w * 64 + jt * 16 + l15;
#pragma unroll
        for (int g = 0; g < 4; ++g) bias[g][jt] = b_ih[g * 256 + col] + b_hh[g * 256 + col];
        wt_r[jt] = Wt[col];
        bt_r[jt] = bt[col];
        wf_r[jt] = Wf[col];
    }

    float cst[4][4];   // fp32 cell state: [jt][reg]
#pragma unroll
    for (int jt = 0; jt < 4; ++jt)
#pragma unroll
        for (int r = 0; r < 4; ++r) cst[jt][r] = 0.f;
    float outp[4] = {0.f, 0.f, 0.f, 0.f};

    // x staging: 256 threads cover 16 rows x 16 chunks of 4 features
    const int xr = tid >> 4;   // row 0..15
    const int xc = tid & 15;   // feature quad 0..15
    const float* xbase = x + (size_t)(b0 + xr) * T_SZ * IN_SZ;

    // prefetch x(t=0)
    float px[4], ptd = 0.f;
    {
        const float* p = xbase;
#pragma unroll
        for (int j = 0; j < 4; ++j) px[j] = p[1 + xc * 4 + j];
        if (xc == 0) ptd = p[0];
    }

    __syncthreads();           // ldsW + A zero visible

    for (int t = 0; t < T_SZ; ++t) {
        // ---- stage x_t (from prefetch regs) + td into LDS
        {
            v4bf vv;
#pragma unroll
            for (int j = 0; j < 4; ++j) vv[j] = (__bf16)px[j];
            *reinterpret_cast<v4bf*>(A + xr * A_STRIDE + xc * 4) = vv;
            if (xc == 0) td_lds[xr] = ptd;
        }
        __syncthreads();   // barrier A: x_t + h(t-1) ready in LDS

        // ---- A fragments + tdv: ALL LDS reads of this step happen here
        // (wave skew: another wave's epilogue(t)/stage(t+1) writes to A/td_lds
        //  must not race our reads -> read everything before barrier B)
        v4i a[NKT];
#pragma unroll
        for (int kt = 0; kt < NKT; ++kt)
            a[kt] = *reinterpret_cast<const v4i*>(A + l15 * A_STRIDE + kt * 32 + lhi * 8);
        float tdv[4];
#pragma unroll
        for (int r = 0; r < 4; ++r) tdv[r] = td_lds[lhi * 4 + r];

        __syncthreads();   // barrier B: below is barrier-free until next barrier A

        // ---- stream prologue: groups 0,1 of kt 6 (8 loads in flight, oldest)
        v4i bs[2][4];
#pragma unroll
        for (int s = 0; s < 2; ++s)
#pragma unroll
            for (int i = 0; i < 4; ++i)
                bs[s][i] = *reinterpret_cast<const v4i*>(
                    wsz_l + (size_t)fid(SKT0, w, s * 4 + i) * 512);

        // ---- x(t+1) prefetch (after stream loads; overlaps GEMM)
        {
            int tn = (t + 1 < T_SZ) ? t + 1 : t;
            const float* p = xbase + (size_t)tn * IN_SZ;
#pragma unroll
            for (int j = 0; j < 4; ++j) px[j] = p[1 + xc * 4 + j];
            if (xc == 0) ptd = p[0];
        }

        f32x4 acc[16];
#pragma unroll
        for (int i = 0; i < 16; ++i) acc[i] = (f32x4){0.f, 0.f, 0.f, 0.f};

        // ---- kt 0..3 from AGPRs (64 MFMA; hides stream latency)
#pragma unroll
        for (int kt = 0; kt < WREG_KT; ++kt)
#pragma unroll
            for (int i = 0; i < 16; ++i)
                mfma_a(acc[i], a[kt], wreg[kt * 16 + i]);

        // ---- kt 4..5 from LDS (32 MFMA)
#pragma unroll
        for (int kt = WREG_KT; kt < SKT0; ++kt)
#pragma unroll
            for (int i = 0; i < 16; ++i) {
                v4i b = *reinterpret_cast<const v4i*>(
                    ldsW + ((size_t)(w * 32 + (kt - WREG_KT) * 16 + i) * 64 + lane) * 8);
                mfma_v(acc[i], a[kt], b);
            }

        // ---- kt 6..9 streamed: 16 groups of 4 frags, 2-deep lookahead
#pragma unroll
        for (int s = 0; s < 16; ++s) {
            int kt = SKT0 + (s >> 2);
            int ib = (s & 3) * 4;
            v4i bc[4];
#pragma unroll
            for (int i = 0; i < 4; ++i) bc[i] = bs[s & 1][i];
            if (s < 14) {   // refill consumed buffer with group s+2
                int sn = s + 2;
                int kn = SKT0 + (sn >> 2);
                int ibn = (sn & 3) * 4;
#pragma unroll
                for (int i = 0; i < 4; ++i)
                    bs[s & 1][i] = *reinterpret_cast<const v4i*>(
                        wsz_l + (size_t)fid(kn, w, ibn + i) * 512);
            }
#pragma unroll
            for (int i = 0; i < 4; ++i)
                mfma_v(acc[ib + i], a[kt], bc[i]);
        }

        // ---- lane-local LSTM epilogue (all 4 gates for this lane's 4 columns)
        const bool last = (t == T_SZ - 1);
#pragma unroll
        for (int jt = 0; jt < 4; ++jt) {
#pragma unroll
            for (int r = 0; r < 4; ++r) {
                float pi = acc[0 * 4 + jt][r] + bias[0][jt];
                float pf = acc[1 * 4 + jt][r] + bias[1][jt];
                float pg = acc[2 * 4 + jt][r] + bias[2][jt];
                float po = acc[3 * 4 + jt][r] + bias[3][jt];
                float d  = fsig(fmaf(tdv[r], wt_r[jt], bt_r[jt]));
                float c  = cst[jt][r] * d;                    // c *= decay
                c = fsig(pf) * c + fsig(pi) * ftanh(pg);      // c = f*c + i*g
                cst[jt][r] = c;
                float h = fsig(po) * ftanh(c);                // h = o*tanh(c)
                int row = lhi * 4 + r;
                int col = w * 64 + jt * 16 + l15;
                A[row * A_STRIDE + 64 + col] = (__bf16)h;     // h -> A layout for next step
                if (last) outp[r] = fmaf(h, wf_r[jt], outp[r]);
            }
        }
    }

    // ---- output: out[b] = h_T . Wf + bf
#pragma unroll
    for (int r = 0; r < 4; ++r) atomicAdd(&out_acc[lhi * 4 + r], outp[r]);
    __syncthreads();
    if (tid < 16) out[b0 + tid] = out_acc[tid] + bfp[0];
}

extern "C" void kernel_launch(void* const* d_in, const int* in_sizes, int n_in,
                              void* d_out, int out_size, void* d_ws, size_t ws_size,
                              hipStream_t stream) {
    const float* x    = (const float*)d_in[0];
    const float* W_ih = (const float*)d_in[1];
    const float* W_hh = (const float*)d_in[2];
    const float* b_ih = (const float*)d_in[3];
    const float* b_hh = (const float*)d_in[4];
    const float* Wt   = (const float*)d_in[5];
    const float* bt   = (const float*)d_in[6];
    const float* Wf   = (const float*)d_in[7];
    const float* bfp  = (const float*)d_in[8];
    float* out  = (float*)d_out;
    __bf16* wsz = (__bf16*)d_ws;   // 640KB of swizzled bf16 W

    (void)in_sizes; (void)n_in; (void)out_size; (void)ws_size;

    hipFuncSetAttribute(reinterpret_cast<const void*>(tlstm_scan),
                        hipFuncAttributeMaxDynamicSharedMemorySize, SMEM_TOTAL);

    prep_w<<<dim3(160), dim3(256), 0, stream>>>(W_ih, W_hh, wsz);
    tlstm_scan<<<dim3(NBLOCKS), dim3(THREADS), SMEM_TOTAL, stream>>>(
        x, wsz, b_ih, b_hh, Wt, bt, Wf, bfp, out);
}